// Round 15
// baseline (281.193 us; speedup 1.0000x reference)
//
#include <hip/hip_runtime.h>
#include <math.h>

#define MAXDEG 64
#define BCAP 8192      // per-bucket capacity (mean ~4096, +64 sigma)
#define EPB 4096       // edges per bucketing block

typedef __attribute__((ext_vector_type(8))) short bf16x8;
typedef __attribute__((ext_vector_type(4))) float f32x4;

// -------------------- bf16 helpers --------------------
static __device__ inline unsigned short f2bf(float f) {
    unsigned int u = __float_as_uint(f);
    u += 0x7FFFu + ((u >> 16) & 1u);  // round-nearest-even
    return (unsigned short)(u >> 16);
}
static __device__ inline float bf2f(unsigned short u) {
    return __uint_as_float(((unsigned int)u) << 16);
}
static __device__ inline float4 ld_f4(const float* p) { return *(const float4*)p; }

// accumulate 16 biased-uint8 (uint4) * scale into 16 f32 (v_cvt_f32_ubyteN)
static __device__ __forceinline__ void accu16(float* a, uint4 u, float f) {
    a[0]  += f * (float)(u.x & 0xffu);
    a[1]  += f * (float)((u.x >> 8) & 0xffu);
    a[2]  += f * (float)((u.x >> 16) & 0xffu);
    a[3]  += f * (float)(u.x >> 24);
    a[4]  += f * (float)(u.y & 0xffu);
    a[5]  += f * (float)((u.y >> 8) & 0xffu);
    a[6]  += f * (float)((u.y >> 16) & 0xffu);
    a[7]  += f * (float)(u.y >> 24);
    a[8]  += f * (float)(u.z & 0xffu);
    a[9]  += f * (float)((u.z >> 8) & 0xffu);
    a[10] += f * (float)((u.z >> 16) & 0xffu);
    a[11] += f * (float)(u.z >> 24);
    a[12] += f * (float)(u.w & 0xffu);
    a[13] += f * (float)((u.w >> 8) & 0xffu);
    a[14] += f * (float)((u.w >> 16) & 0xffu);
    a[15] += f * (float)(u.w >> 24);
}

// ==================== K0: weight transposes to bf16 ====================
static __global__ __launch_bounds__(256) void wtrans_kernel(
    const float* __restrict__ W1, const float* __restrict__ Wh,
    const float* __restrict__ W2,
    unsigned short* __restrict__ W1t, unsigned short* __restrict__ WhT,
    unsigned short* __restrict__ Wt2) {
    int b = blockIdx.x;
    int t = threadIdx.x;
    if (b == 2) {
        for (int i = t; i < 48 * 128; i += 256) Wt2[i] = 0;
        __syncthreads();
        int n0 = (t & 31) * 4;
        if (n0 < 40) {
            for (int k = t >> 5; k < 128; k += 8) {
                float4 v = ld_f4(&W2[(size_t)k * 40 + n0]);
                Wt2[(size_t)(n0 + 0) * 128 + k] = f2bf(v.x);
                Wt2[(size_t)(n0 + 1) * 128 + k] = f2bf(v.y);
                Wt2[(size_t)(n0 + 2) * 128 + k] = f2bf(v.z);
                Wt2[(size_t)(n0 + 3) * 128 + k] = f2bf(v.w);
            }
        }
        return;
    }
    const float* Wsrc = (b == 0) ? W1 : Wh;
    unsigned short* Wdst = (b == 0) ? W1t : WhT;
    int n0 = (t & 31) * 4;
    for (int k = t >> 5; k < 128; k += 8) {
        float4 v = ld_f4(&Wsrc[(size_t)k * 128 + n0]);
        Wdst[(size_t)(n0 + 0) * 128 + k] = f2bf(v.x);
        Wdst[(size_t)(n0 + 1) * 128 + k] = f2bf(v.y);
        Wdst[(size_t)(n0 + 2) * 128 + k] = f2bf(v.z);
        Wdst[(size_t)(n0 + 3) * 128 + k] = f2bf(v.w);
    }
}

// -------------------- MFMA GEMM phases --------------------
// 256-thread (4 waves): C = sa16 @ Wt^T -> biased-uint8 Y + per-row scale
static __device__ __forceinline__ void gemm128_mfma256_q(
    const unsigned short* sa16, const unsigned short* __restrict__ Wt,
    unsigned char* __restrict__ Y, float* __restrict__ sc,
    int row0, int t, int N) {
    int l = t & 63, w = t >> 6;
    int m = l & 15, kg = l >> 4;
    int row = w * 16 + m;
    int rsw = row & 15;
    f32x4 acc[8];
#pragma unroll
    for (int c = 0; c < 8; ++c) acc[c] = (f32x4){0.f, 0.f, 0.f, 0.f};
#pragma unroll
    for (int ks = 0; ks < 4; ++ks) {
        bf16x8 a = *(const bf16x8*)&sa16[(size_t)row * 128 + (((ks * 4 + kg) ^ rsw) * 8)];
        int kk = ks * 32 + kg * 8;
#pragma unroll
        for (int c = 0; c < 8; ++c) {
            bf16x8 b = *(const bf16x8*)&Wt[(size_t)(c * 16 + m) * 128 + kk];
            acc[c] = __builtin_amdgcn_mfma_f32_16x16x32_bf16(a, b, acc[c], 0, 0, 0);
        }
    }
#pragma unroll
    for (int r = 0; r < 4; ++r) {
        float lm = 0.f;
#pragma unroll
        for (int c = 0; c < 8; ++c) lm = fmaxf(lm, fabsf(acc[c][r]));
#pragma unroll
        for (int o = 1; o < 16; o <<= 1) lm = fmaxf(lm, __shfl_xor(lm, o));
        float inv = lm > 0.f ? 127.f / lm : 0.f;
        int grow = row0 + w * 16 + kg * 4 + r;
        if (grow < N) {
#pragma unroll
            for (int c = 0; c < 8; ++c)
                Y[(size_t)grow * 128 + c * 16 + m] =
                    (unsigned char)(__float2int_rn(acc[c][r] * inv) + 128);
            if (m == 0) sc[grow] = lm * (1.f / 127.f);
        }
    }
}

// 512-thread (8 waves) -> biased-uint8 Y + per-row scale (LDS atomicMax)
static __device__ __forceinline__ void gemm128_mfma512_q(
    const unsigned short* sa16, const unsigned short* __restrict__ Wt,
    unsigned char* __restrict__ Y, float* __restrict__ sc,
    unsigned* rmaxu, int row0, int t, int N) {
    int l = t & 63, w = t >> 6;
    int rt = w >> 1, ctb = (w & 1) * 4;
    int m = l & 15, kg = l >> 4;
    int row = rt * 16 + m;
    int rsw = row & 15;
    f32x4 acc[4] = {{0.f, 0.f, 0.f, 0.f}, {0.f, 0.f, 0.f, 0.f},
                    {0.f, 0.f, 0.f, 0.f}, {0.f, 0.f, 0.f, 0.f}};
#pragma unroll
    for (int ks = 0; ks < 4; ++ks) {
        bf16x8 a = *(const bf16x8*)&sa16[(size_t)row * 128 + (((ks * 4 + kg) ^ rsw) * 8)];
        int kk = ks * 32 + kg * 8;
#pragma unroll
        for (int c = 0; c < 4; ++c) {
            int n = (ctb + c) * 16 + m;
            bf16x8 b = *(const bf16x8*)&Wt[(size_t)n * 128 + kk];
            acc[c] = __builtin_amdgcn_mfma_f32_16x16x32_bf16(a, b, acc[c], 0, 0, 0);
        }
    }
#pragma unroll
    for (int r = 0; r < 4; ++r) {
        float lm = 0.f;
#pragma unroll
        for (int c = 0; c < 4; ++c) lm = fmaxf(lm, fabsf(acc[c][r]));
#pragma unroll
        for (int o = 1; o < 16; o <<= 1) lm = fmaxf(lm, __shfl_xor(lm, o));
        if (m == 0)
            atomicMax(&rmaxu[rt * 16 + kg * 4 + r], __float_as_uint(lm));
    }
    __syncthreads();
#pragma unroll
    for (int r = 0; r < 4; ++r) {
        int rl = rt * 16 + kg * 4 + r;
        float am = __uint_as_float(rmaxu[rl]);
        float inv = am > 0.f ? 127.f / am : 0.f;
        int grow = row0 + rl;
        if (grow < N) {
#pragma unroll
            for (int c = 0; c < 4; ++c)
                Y[(size_t)grow * 128 + (ctb + c) * 16 + m] =
                    (unsigned char)(__float2int_rn(acc[c][r] * inv) + 128);
            if (ctb == 0 && m == 0) sc[grow] = am * (1.f / 127.f);
        }
    }
}

// C[64x40] = sa16 @ Wt2^T -> bf16 Y3
static __device__ __forceinline__ void gemm40_mfma512(
    const unsigned short* sa16, const unsigned short* __restrict__ Wt2,
    unsigned short* __restrict__ Y3, int row0, int t, int N) {
    int l = t & 63, w = t >> 6;
    int rt = w & 3;
    int nct = (w < 4) ? 2 : 1;
    int ct0 = (w < 4) ? 0 : 2;
    int m = l & 15, kg = l >> 4;
    int row = rt * 16 + m;
    int rsw = row & 15;
    f32x4 acc[2] = {{0.f, 0.f, 0.f, 0.f}, {0.f, 0.f, 0.f, 0.f}};
#pragma unroll
    for (int ks = 0; ks < 4; ++ks) {
        bf16x8 a = *(const bf16x8*)&sa16[(size_t)row * 128 + (((ks * 4 + kg) ^ rsw) * 8)];
        int kk = ks * 32 + kg * 8;
        for (int c = 0; c < nct; ++c) {
            int n = (ct0 + c) * 16 + m;
            bf16x8 b = *(const bf16x8*)&Wt2[(size_t)n * 128 + kk];
            acc[c] = __builtin_amdgcn_mfma_f32_16x16x32_bf16(a, b, acc[c], 0, 0, 0);
        }
    }
    for (int c = 0; c < nct; ++c) {
        int col = (ct0 + c) * 16 + m;
        if (col >= 40) continue;
#pragma unroll
        for (int r = 0; r < 4; ++r) {
            int grow = row0 + rt * 16 + kg * 4 + r;
            if (grow < N) Y3[(size_t)grow * 40 + col] = f2bf(acc[c][r]);
        }
    }
}

// ------ biased-u8 gather v2 (512 thr): 8 lanes/row, 16B/lane, 1 load/edge -
// Eighth (8 lanes) owns a row; lane loads uint4 = full 128B row per edge in
// ONE wave instruction. 8 rows per wave -> no outer row loop, no cross-lane
// reduce. Degrees <=32 staged in regs; rare d>32 tail via broadcast loads.
template <int MODE>
static __device__ __forceinline__ void gather_phase_u8(
    const unsigned char* __restrict__ Ysrc, const float* __restrict__ scs,
    unsigned short* sa16,
    const int* __restrict__ csr, const int* __restrict__ indeg,
    const int* __restrict__ outdeg, int row0, int t, int N) {
    int w = t >> 6;             // wave 0..7
    int l = t & 63;
    int g8 = l >> 3;            // eighth 0..7 (one row each)
    int le = l & 7;             // lane within eighth
    int gb = g8 * 8;            // eighth's base lane in wave

    int r = w * 8 + g8;         // 0..63 (one row per eighth, no loop)
    int node = row0 + r;
    bool valid = node < N;
    int d = 0;
    if (valid) d = indeg[node];
    int dc = d > MAXDEG ? MAXDEG : d;
    int dc32 = dc > 32 ? 32 : dc;

    // stage first 32 edges + scales across the eighth (scale 0 = inactive)
    const int* cp = csr + (size_t)node * MAXDEG;
    int idx0 = 0, idx1 = 0, idx2 = 0, idx3 = 0;
    float sv0 = 0.f, sv1 = 0.f, sv2 = 0.f, sv3 = 0.f;
    if (valid) {
        if (le < dc32)      { idx0 = cp[le];      sv0 = scs[idx0]; }
        if (le + 8 < dc32)  { idx1 = cp[le + 8];  sv1 = scs[idx1]; }
        if (le + 16 < dc32) { idx2 = cp[le + 16]; sv2 = scs[idx2]; }
        if (le + 24 < dc32) { idx3 = cp[le + 24]; sv3 = scs[idx3]; }
    }

    float a[16];
#pragma unroll
    for (int x = 0; x < 16; ++x) a[x] = 0.f;
    float S = 0.f;

#pragma unroll
    for (int c = 0; c < 4; ++c) {
        int ebase = c * 8;
        if (ebase >= dc32) break;
        int v = (c == 0) ? idx0 : (c == 1) ? idx1 : (c == 2) ? idx2 : idx3;
        float vs = (c == 0) ? sv0 : (c == 1) ? sv1 : (c == 2) ? sv2 : sv3;
        int lim = dc32 - ebase;
        if (lim > 8) lim = 8;
        int e = 0;
        for (; e + 4 <= lim; e += 4) {
            int s0 = __shfl(v, gb + e);
            int s1 = __shfl(v, gb + e + 1);
            int s2 = __shfl(v, gb + e + 2);
            int s3 = __shfl(v, gb + e + 3);
            float f0 = __shfl(vs, gb + e);
            float f1 = __shfl(vs, gb + e + 1);
            float f2 = __shfl(vs, gb + e + 2);
            float f3 = __shfl(vs, gb + e + 3);
            uint4 u0 = *(const uint4*)&Ysrc[(size_t)s0 * 128 + le * 16];
            uint4 u1 = *(const uint4*)&Ysrc[(size_t)s1 * 128 + le * 16];
            uint4 u2 = *(const uint4*)&Ysrc[(size_t)s2 * 128 + le * 16];
            uint4 u3 = *(const uint4*)&Ysrc[(size_t)s3 * 128 + le * 16];
            S += f0 + f1 + f2 + f3;
            accu16(a, u0, f0); accu16(a, u1, f1);
            accu16(a, u2, f2); accu16(a, u3, f3);
        }
        for (; e < lim; ++e) {
            int s0 = __shfl(v, gb + e);
            float f0 = __shfl(vs, gb + e);
            uint4 u0 = *(const uint4*)&Ysrc[(size_t)s0 * 128 + le * 16];
            S += f0;
            accu16(a, u0, f0);
        }
    }
    // rare tail: degree 33..64 (P ~ 1e-4), broadcast loads within eighth
    if (valid) {
        for (int e = 32; e < dc; ++e) {
            int s = cp[e];
            float f = scs[s];
            uint4 u = *(const uint4*)&Ysrc[(size_t)s * 128 + le * 16];
            S += f;
            accu16(a, u, f);
        }
    }

    if (valid) {
        float bias = 128.f * S;
        int od = outdeg[node];
        float ln = rsqrtf((float)(od > 1 ? od : 1));
        if (MODE == 0) {
#pragma unroll
            for (int x = 0; x < 16; ++x)
                a[x] = fmaxf(a[x] - bias, 0.f) * ln;
        } else {
            float rn = rsqrtf((float)(d > 1 ? d : 1));
#pragma unroll
            for (int x = 0; x < 16; ++x)
                a[x] = fmaxf((a[x] - bias) * rn, 0.f) * ln;
        }
    } else {
#pragma unroll
        for (int x = 0; x < 16; ++x) a[x] = 0.f;
    }

    // write 2 adjacent-pair swizzled chunks (dims le*16..+7, +8..+15)
    int rsw = r & 15;
    uint4 uo0, uo1;
    uo0.x = (unsigned)f2bf(a[0]) | ((unsigned)f2bf(a[1]) << 16);
    uo0.y = (unsigned)f2bf(a[2]) | ((unsigned)f2bf(a[3]) << 16);
    uo0.z = (unsigned)f2bf(a[4]) | ((unsigned)f2bf(a[5]) << 16);
    uo0.w = (unsigned)f2bf(a[6]) | ((unsigned)f2bf(a[7]) << 16);
    uo1.x = (unsigned)f2bf(a[8]) | ((unsigned)f2bf(a[9]) << 16);
    uo1.y = (unsigned)f2bf(a[10]) | ((unsigned)f2bf(a[11]) << 16);
    uo1.z = (unsigned)f2bf(a[12]) | ((unsigned)f2bf(a[13]) << 16);
    uo1.w = (unsigned)f2bf(a[14]) | ((unsigned)f2bf(a[15]) << 16);
    *(uint4*)&sa16[(size_t)r * 128 + ((2 * le) ^ rsw) * 8] = uo0;
    *(uint4*)&sa16[(size_t)r * 128 + ((2 * le + 1) ^ rsw) * 8] = uo1;
}

// ==================== K1: edge bucketing || GEMM1 (MFMA, u8 out) ========
static __global__ __launch_bounds__(256) void bucket_gemm1_kernel(
    const float* __restrict__ A, const unsigned short* __restrict__ W1t,
    unsigned char* __restrict__ Y, float* __restrict__ s1,
    const int* __restrict__ src, const int* __restrict__ dst,
    int* __restrict__ cntD, int* __restrict__ cntS,
    unsigned int* __restrict__ bktD, unsigned char* __restrict__ bktS,
    int N, int E, int nb, int gG, int gB) {
    __shared__ unsigned short sa16[64 * 128];  // 16 KB; bucket role aliases
    int bid = blockIdx.x;
    int t = threadIdx.x;

    int nI = 5 * gB;
    int role, idx;
    if (bid < nI) {
        if (bid % 5 == 0) { role = 1; idx = bid / 5; }
        else { role = 0; idx = bid - bid / 5 - 1; }
    } else { role = 0; idx = bid - gB; }
    if (role == 1 && idx >= gB) return;
    if (role == 0 && idx >= gG) return;

    if (role == 1) {
        int* sh = (int*)sa16;    // 12 KB of the 16 KB
        int* hD = sh;
        int* hS = sh + 512;
        int* bD = sh + 1024;
        int* bS = sh + 1536;
        int* cD = sh + 2048;
        int* cS = sh + 2560;
        for (int i = t; i < 512; i += 256) {
            hD[i] = 0; hS[i] = 0; cD[i] = 0; cS[i] = 0;
        }
        __syncthreads();

        int base = idx * EPB + t * 16;
        int s_r[16], d_r[16];
        int nv = 0;
        if (base + 16 <= E) {
            nv = 16;
#pragma unroll
            for (int k = 0; k < 4; ++k) {
                int4 sv = *(const int4*)&src[base + k * 4];
                int4 dv = *(const int4*)&dst[base + k * 4];
                s_r[k * 4 + 0] = sv.x; s_r[k * 4 + 1] = sv.y;
                s_r[k * 4 + 2] = sv.z; s_r[k * 4 + 3] = sv.w;
                d_r[k * 4 + 0] = dv.x; d_r[k * 4 + 1] = dv.y;
                d_r[k * 4 + 2] = dv.z; d_r[k * 4 + 3] = dv.w;
            }
        } else {
            nv = E - base; if (nv < 0) nv = 0; if (nv > 16) nv = 16;
#pragma unroll
            for (int k = 0; k < 16; ++k) {
                if (k < nv) { s_r[k] = src[base + k]; d_r[k] = dst[base + k]; }
                else { s_r[k] = 0; d_r[k] = 0; }
            }
        }

#pragma unroll
        for (int k = 0; k < 16; ++k) {
            if (k < nv) {
                atomicAdd(&hD[d_r[k] >> 8], 1);
                atomicAdd(&hS[s_r[k] >> 8], 1);
            }
        }
        __syncthreads();

        for (int b = t; b < nb; b += 256) {
            int h = hD[b];
            bD[b] = h ? atomicAdd(&cntD[b], h) : 0;
            int h2 = hS[b];
            bS[b] = h2 ? atomicAdd(&cntS[b], h2) : 0;
        }
        __syncthreads();

#pragma unroll
        for (int k = 0; k < 16; ++k) {
            if (k < nv) {
                int d = d_r[k], s = s_r[k];
                int bb = d >> 8;
                int p = atomicAdd(&cD[bb], 1) + bD[bb];
                if (p < BCAP)
                    bktD[(size_t)bb * BCAP + p] =
                        ((unsigned int)(d & 255) << 17) | (unsigned int)s;
                int sb = s >> 8;
                int p2 = atomicAdd(&cS[sb], 1) + bS[sb];
                if (p2 < BCAP)
                    bktS[(size_t)sb * BCAP + p2] = (unsigned char)(s & 255);
            }
        }
        return;
    }

    // ---- gemm1: stage fp32 features -> bf16 swizzled LDS ----
    int row0 = idx * 64;
#pragma unroll
    for (int i = 0; i < 4; ++i) {
        int ci = i * 256 + t;
        int r = ci >> 4;
        int ch = ci & 15;
        int grow = row0 + r;
        uint4 uo = make_uint4(0u, 0u, 0u, 0u);
        if (grow < N) {
            float4 v0 = ld_f4(&A[(size_t)grow * 128 + ch * 8]);
            float4 v1 = ld_f4(&A[(size_t)grow * 128 + ch * 8 + 4]);
            uo.x = (unsigned)f2bf(v0.x) | ((unsigned)f2bf(v0.y) << 16);
            uo.y = (unsigned)f2bf(v0.z) | ((unsigned)f2bf(v0.w) << 16);
            uo.z = (unsigned)f2bf(v1.x) | ((unsigned)f2bf(v1.y) << 16);
            uo.w = (unsigned)f2bf(v1.z) | ((unsigned)f2bf(v1.w) << 16);
        }
        int chunk = ch ^ (r & 15);
        *(uint4*)&sa16[(size_t)r * 128 + chunk * 8] = uo;
    }
    __syncthreads();
    gemm128_mfma256_q(sa16, W1t, Y, s1, row0, t, N);
}

// ==================== K1b: per-bucket CSR build ====================
static __global__ __launch_bounds__(256) void csr_build_kernel(
    const int* __restrict__ cntD, const int* __restrict__ cntS,
    const unsigned int* __restrict__ bktD, const unsigned char* __restrict__ bktS,
    int* __restrict__ csr, int* __restrict__ indeg, int* __restrict__ outdeg,
    int N, int nb) {
    __shared__ int cur[256];
    int bid = blockIdx.x;
    int t = threadIdx.x;
    cur[t] = 0;
    __syncthreads();

    if (bid < nb) {
        int b = bid;
        int cnt = cntD[b]; if (cnt > BCAP) cnt = BCAP;
        const unsigned int* bp = bktD + (size_t)b * BCAP;
        for (int i = t; i < cnt; i += 256) {
            unsigned int v = bp[i];
            int d8 = v >> 17;
            int s = (int)(v & 0x1FFFFu);
            int p = atomicAdd(&cur[d8], 1);
            if (p < MAXDEG) csr[((size_t)(b * 256 + d8)) * MAXDEG + p] = s;
        }
        __syncthreads();
        int node = b * 256 + t;
        if (node < N) indeg[node] = cur[t];
    } else {
        int b = bid - nb;
        int cnt = cntS[b]; if (cnt > BCAP) cnt = BCAP;
        const unsigned char* bp = bktS + (size_t)b * BCAP;
        for (int i = t; i < cnt; i += 256) atomicAdd(&cur[bp[i]], 1);
        __syncthreads();
        int node = b * 256 + t;
        if (node < N) outdeg[node] = cur[t];
    }
}

// ==================== K2: agg(Y1 u8)+relu+ln @ Wh (MFMA, u8 out) ======
static __global__ __launch_bounds__(512) void agg_gemm2_kernel(
    const unsigned char* __restrict__ Y1, const float* __restrict__ s1,
    const unsigned short* __restrict__ WhT,
    unsigned char* __restrict__ Y2, float* __restrict__ s2,
    const int* __restrict__ csr, const int* __restrict__ indeg,
    const int* __restrict__ outdeg, int N) {
    __shared__ unsigned short sa16[64 * 128];  // 16 KB
    __shared__ unsigned rmaxu[64];
    int t = threadIdx.x;
    if (t < 64) rmaxu[t] = 0u;
    int row0 = blockIdx.x * 64;
    gather_phase_u8<0>(Y1, s1, sa16, csr, indeg, outdeg, row0, t, N);
    __syncthreads();
    gemm128_mfma512_q(sa16, WhT, Y2, s2, rmaxu, row0, t, N);
}

// ==================== K3: agg(Y2 u8)*rn,relu,*ln @ W2 (MFMA) ============
static __global__ __launch_bounds__(512) void agg_gemm3_kernel(
    const unsigned char* __restrict__ Y2, const float* __restrict__ s2,
    const unsigned short* __restrict__ Wt2,
    unsigned short* __restrict__ Y3,
    const int* __restrict__ csr, const int* __restrict__ indeg,
    const int* __restrict__ outdeg, int N) {
    __shared__ unsigned short sa16[64 * 128];  // 16 KB
    int t = threadIdx.x;
    int row0 = blockIdx.x * 64;
    gather_phase_u8<1>(Y2, s2, sa16, csr, indeg, outdeg, row0, t, N);
    __syncthreads();
    gemm40_mfma512(sa16, Wt2, Y3, row0, t, N);
}

// ========== K4: agg(Y3)*rn + b2 + log_softmax ==========
static __global__ __launch_bounds__(512) void agg40_lsm_kernel(
    const unsigned short* __restrict__ Y3, const float* __restrict__ b2,
    const int* __restrict__ csr, const int* __restrict__ indeg,
    float* __restrict__ out, int N) {
    int t = threadIdx.x;
    int node = blockIdx.x * 8 + (t >> 6);
    if (node >= N) return;
    int lane = t & 63;
    int grp = lane >> 4;
    int sub = lane & 15;
    int d = indeg[node];
    int dc = d > MAXDEG ? MAXDEG : d;

    float a0 = 0.f, a1 = 0.f, a2 = 0.f, a3 = 0.f;
    if (sub < 10) {
        const int* cp = csr + (size_t)node * MAXDEG;
        int e = grp;
        for (; e + 12 < dc; e += 16) {
            int s0 = cp[e];
            int s1 = cp[e + 4];
            int s2 = cp[e + 8];
            int s3 = cp[e + 12];
            ushort4 u0 = *(const ushort4*)&Y3[(size_t)s0 * 40 + sub * 4];
            ushort4 u1 = *(const ushort4*)&Y3[(size_t)s1 * 40 + sub * 4];
            ushort4 u2 = *(const ushort4*)&Y3[(size_t)s2 * 40 + sub * 4];
            ushort4 u3 = *(const ushort4*)&Y3[(size_t)s3 * 40 + sub * 4];
            a0 += bf2f(u0.x) + bf2f(u1.x) + bf2f(u2.x) + bf2f(u3.x);
            a1 += bf2f(u0.y) + bf2f(u1.y) + bf2f(u2.y) + bf2f(u3.y);
            a2 += bf2f(u0.z) + bf2f(u1.z) + bf2f(u2.z) + bf2f(u3.z);
            a3 += bf2f(u0.w) + bf2f(u1.w) + bf2f(u2.w) + bf2f(u3.w);
        }
        for (; e < dc; e += 4) {
            int s = cp[e];
            ushort4 u = *(const ushort4*)&Y3[(size_t)s * 40 + sub * 4];
            a0 += bf2f(u.x); a1 += bf2f(u.y); a2 += bf2f(u.z); a3 += bf2f(u.w);
        }
    }
    a0 += __shfl_xor(a0, 16); a0 += __shfl_xor(a0, 32);
    a1 += __shfl_xor(a1, 16); a1 += __shfl_xor(a1, 32);
    a2 += __shfl_xor(a2, 16); a2 += __shfl_xor(a2, 32);
    a3 += __shfl_xor(a3, 16); a3 += __shfl_xor(a3, 32);

    float rs = rsqrtf((float)(d > 1 ? d : 1));
    float x0 = 0.f, x1 = 0.f, x2 = 0.f, x3 = 0.f;
    float mx = -INFINITY;
    if (sub < 10) {
        float4 b = *(const float4*)&b2[sub * 4];
        x0 = a0 * rs + b.x;
        x1 = a1 * rs + b.y;
        x2 = a2 * rs + b.z;
        x3 = a3 * rs + b.w;
        mx = fmaxf(fmaxf(x0, x1), fmaxf(x2, x3));
    }
#pragma unroll
    for (int o = 1; o < 16; o <<= 1) mx = fmaxf(mx, __shfl_xor(mx, o));
    float ex = 0.f;
    if (sub < 10)
        ex = expf(x0 - mx) + expf(x1 - mx) + expf(x2 - mx) + expf(x3 - mx);
#pragma unroll
    for (int o = 1; o < 16; o <<= 1) ex += __shfl_xor(ex, o);
    float ls = logf(ex) + mx;
    if (sub < 10 && grp == 0)
        *(float4*)&out[(size_t)node * 40 + sub * 4] =
            make_float4(x0 - ls, x1 - ls, x2 - ls, x3 - ls);
}

// -------------------- launch --------------------

extern "C" void kernel_launch(void* const* d_in, const int* in_sizes, int n_in,
                              void* d_out, int out_size, void* d_ws, size_t ws_size,
                              hipStream_t stream) {
    const float* features = (const float*)d_in[0];
    const int* src = (const int*)d_in[1];
    const int* dst = (const int*)d_in[2];
    const float* W1 = (const float*)d_in[3];
    const float* Wh = (const float*)d_in[4];
    const float* W2 = (const float*)d_in[5];
    const float* b2 = (const float*)d_in[6];
    float* out = (float*)d_out;

    const int N = in_sizes[0] / 128;
    const int E = in_sizes[1];
    const int nb = (N + 255) / 256;

    char* p = (char*)d_ws;
    auto carve = [&](size_t bytes) {
        char* q = p;
        p += (bytes + 255) & ~(size_t)255;
        return q;
    };
    unsigned char* bufY1 = (unsigned char*)carve((size_t)N * 128);
    float* sc1 = (float*)carve((size_t)N * 4);
    unsigned char* bufY2 = (unsigned char*)carve((size_t)N * 128);
    float* sc2 = (float*)carve((size_t)N * 4);
    unsigned short* bufY3 = (unsigned short*)carve((size_t)N * 40 * 2);
    int* csr = (int*)carve((size_t)N * MAXDEG * 4);
    unsigned int* bktD = (unsigned int*)carve((size_t)nb * BCAP * 4);
    unsigned char* bktS = (unsigned char*)carve((size_t)nb * BCAP);
    int* cntD = (int*)carve((size_t)nb * 4);
    int* cntS = (int*)carve((size_t)nb * 4);
    int* indeg = (int*)carve((size_t)N * 4);
    int* outdeg = (int*)carve((size_t)N * 4);
    unsigned short* W1t = (unsigned short*)carve((size_t)128 * 128 * 2);
    unsigned short* WhT = (unsigned short*)carve((size_t)128 * 128 * 2);
    unsigned short* Wt2 = (unsigned short*)carve((size_t)48 * 128 * 2);
    (void)ws_size; (void)n_in; (void)out_size;

    hipMemsetAsync(cntD, 0, (size_t)nb * 4, stream);
    hipMemsetAsync(cntS, 0, (size_t)nb * 4, stream);

    int gG = (N + 63) / 64;
    int gB = (E + EPB - 1) / EPB;
    // K0: weight transposes (bf16)
    wtrans_kernel<<<3, 256, 0, stream>>>(W1, Wh, W2, W1t, WhT, Wt2);
    // K1: edge bucketing || gemm1 (MFMA, u8+scale out)
    bucket_gemm1_kernel<<<gG + gB, 256, 0, stream>>>(
        features, W1t, bufY1, sc1, src, dst, cntD, cntS, bktD, bktS,
        N, E, nb, gG, gB);
    // K1b: per-bucket CSR/indeg/outdeg
    csr_build_kernel<<<2 * nb, 256, 0, stream>>>(
        cntD, cntS, bktD, bktS, csr, indeg, outdeg, N, nb);
    // K2: Y2 = (relu(agg(Y1)) * ln) @ Wh   (u8 gather v2, MFMA, u8 out)
    agg_gemm2_kernel<<<gG, 512, 0, stream>>>(bufY1, sc1, WhT, bufY2, sc2,
                                             csr, indeg, outdeg, N);
    // K3: Y3 = (relu(agg(Y2) * rn) * ln) @ W2  (u8 gather v2, MFMA)
    agg_gemm3_kernel<<<gG, 512, 0, stream>>>(bufY2, sc2, Wt2, bufY3,
                                             csr, indeg, outdeg, N);
    // K4: out = log_softmax(agg(Y3) * rn + b2)
    agg40_lsm_kernel<<<(N + 7) / 8, 512, 0, stream>>>(bufY3, b2, csr, indeg, out, N);
}

// Round 16
// 270.465 us; speedup vs baseline: 1.0397x; 1.0397x over previous
//
#include <hip/hip_runtime.h>
#include <math.h>

#define MAXDEG 64
#define BCAP 8192      // per-bucket capacity (mean ~4096, +64 sigma)
#define EPB 4096       // edges per bucketing block

typedef __attribute__((ext_vector_type(8))) short bf16x8;
typedef __attribute__((ext_vector_type(4))) float f32x4;

// -------------------- bf16 helpers --------------------
static __device__ inline unsigned short f2bf(float f) {
    unsigned int u = __float_as_uint(f);
    u += 0x7FFFu + ((u >> 16) & 1u);  // round-nearest-even
    return (unsigned short)(u >> 16);
}
static __device__ inline float bf2f(unsigned short u) {
    return __uint_as_float(((unsigned int)u) << 16);
}
static __device__ inline float4 ld_f4(const float* p) { return *(const float4*)p; }

// accumulate 8 int8 (packed in uint2) * scale into 8 f32
static __device__ __forceinline__ void acci8(float* a, uint2 u, float s) {
    a[0] += s * (float)((int)(u.x << 24) >> 24);
    a[1] += s * (float)((int)(u.x << 16) >> 24);
    a[2] += s * (float)((int)(u.x << 8) >> 24);
    a[3] += s * (float)((int)u.x >> 24);
    a[4] += s * (float)((int)(u.y << 24) >> 24);
    a[5] += s * (float)((int)(u.y << 16) >> 24);
    a[6] += s * (float)((int)(u.y << 8) >> 24);
    a[7] += s * (float)((int)u.y >> 24);
}

// ==================== K0: weight transposes to bf16 ====================
static __global__ __launch_bounds__(256) void wtrans_kernel(
    const float* __restrict__ W1, const float* __restrict__ Wh,
    const float* __restrict__ W2,
    unsigned short* __restrict__ W1t, unsigned short* __restrict__ WhT,
    unsigned short* __restrict__ Wt2) {
    int b = blockIdx.x;
    int t = threadIdx.x;
    if (b == 2) {
        for (int i = t; i < 48 * 128; i += 256) Wt2[i] = 0;
        __syncthreads();
        int n0 = (t & 31) * 4;
        if (n0 < 40) {
            for (int k = t >> 5; k < 128; k += 8) {
                float4 v = ld_f4(&W2[(size_t)k * 40 + n0]);
                Wt2[(size_t)(n0 + 0) * 128 + k] = f2bf(v.x);
                Wt2[(size_t)(n0 + 1) * 128 + k] = f2bf(v.y);
                Wt2[(size_t)(n0 + 2) * 128 + k] = f2bf(v.z);
                Wt2[(size_t)(n0 + 3) * 128 + k] = f2bf(v.w);
            }
        }
        return;
    }
    const float* Wsrc = (b == 0) ? W1 : Wh;
    unsigned short* Wdst = (b == 0) ? W1t : WhT;
    int n0 = (t & 31) * 4;
    for (int k = t >> 5; k < 128; k += 8) {
        float4 v = ld_f4(&Wsrc[(size_t)k * 128 + n0]);
        Wdst[(size_t)(n0 + 0) * 128 + k] = f2bf(v.x);
        Wdst[(size_t)(n0 + 1) * 128 + k] = f2bf(v.y);
        Wdst[(size_t)(n0 + 2) * 128 + k] = f2bf(v.z);
        Wdst[(size_t)(n0 + 3) * 128 + k] = f2bf(v.w);
    }
}

// -------------------- MFMA GEMM phases --------------------
// 256-thread (4 waves): C = sa16 @ Wt^T -> int8 Y + per-row scale
static __device__ __forceinline__ void gemm128_mfma256_q(
    const unsigned short* sa16, const unsigned short* __restrict__ Wt,
    signed char* __restrict__ Y, float* __restrict__ sc,
    int row0, int t, int N) {
    int l = t & 63, w = t >> 6;
    int m = l & 15, kg = l >> 4;
    int row = w * 16 + m;
    int rsw = row & 15;
    f32x4 acc[8];
#pragma unroll
    for (int c = 0; c < 8; ++c) acc[c] = (f32x4){0.f, 0.f, 0.f, 0.f};
#pragma unroll
    for (int ks = 0; ks < 4; ++ks) {
        bf16x8 a = *(const bf16x8*)&sa16[(size_t)row * 128 + (((ks * 4 + kg) ^ rsw) * 8)];
        int kk = ks * 32 + kg * 8;
#pragma unroll
        for (int c = 0; c < 8; ++c) {
            bf16x8 b = *(const bf16x8*)&Wt[(size_t)(c * 16 + m) * 128 + kk];
            acc[c] = __builtin_amdgcn_mfma_f32_16x16x32_bf16(a, b, acc[c], 0, 0, 0);
        }
    }
#pragma unroll
    for (int r = 0; r < 4; ++r) {
        float lm = 0.f;
#pragma unroll
        for (int c = 0; c < 8; ++c) lm = fmaxf(lm, fabsf(acc[c][r]));
#pragma unroll
        for (int o = 1; o < 16; o <<= 1) lm = fmaxf(lm, __shfl_xor(lm, o));
        float inv = lm > 0.f ? 127.f / lm : 0.f;
        int grow = row0 + w * 16 + kg * 4 + r;
        if (grow < N) {
#pragma unroll
            for (int c = 0; c < 8; ++c)
                Y[(size_t)grow * 128 + c * 16 + m] =
                    (signed char)__float2int_rn(acc[c][r] * inv);
            if (m == 0) sc[grow] = lm * (1.f / 127.f);
        }
    }
}

// 512-thread (8 waves) -> int8 Y + per-row scale (cross-wave LDS atomicMax)
static __device__ __forceinline__ void gemm128_mfma512_q(
    const unsigned short* sa16, const unsigned short* __restrict__ Wt,
    signed char* __restrict__ Y, float* __restrict__ sc,
    unsigned* rmaxu, int row0, int t, int N) {
    int l = t & 63, w = t >> 6;
    int rt = w >> 1, ctb = (w & 1) * 4;
    int m = l & 15, kg = l >> 4;
    int row = rt * 16 + m;
    int rsw = row & 15;
    f32x4 acc[4] = {{0.f, 0.f, 0.f, 0.f}, {0.f, 0.f, 0.f, 0.f},
                    {0.f, 0.f, 0.f, 0.f}, {0.f, 0.f, 0.f, 0.f}};
#pragma unroll
    for (int ks = 0; ks < 4; ++ks) {
        bf16x8 a = *(const bf16x8*)&sa16[(size_t)row * 128 + (((ks * 4 + kg) ^ rsw) * 8)];
        int kk = ks * 32 + kg * 8;
#pragma unroll
        for (int c = 0; c < 4; ++c) {
            int n = (ctb + c) * 16 + m;
            bf16x8 b = *(const bf16x8*)&Wt[(size_t)n * 128 + kk];
            acc[c] = __builtin_amdgcn_mfma_f32_16x16x32_bf16(a, b, acc[c], 0, 0, 0);
        }
    }
    // per-row absmax: in-wave reduce over m, cross-wave via LDS
#pragma unroll
    for (int r = 0; r < 4; ++r) {
        float lm = 0.f;
#pragma unroll
        for (int c = 0; c < 4; ++c) lm = fmaxf(lm, fabsf(acc[c][r]));
#pragma unroll
        for (int o = 1; o < 16; o <<= 1) lm = fmaxf(lm, __shfl_xor(lm, o));
        if (m == 0)
            atomicMax(&rmaxu[rt * 16 + kg * 4 + r], __float_as_uint(lm));
    }
    __syncthreads();
#pragma unroll
    for (int r = 0; r < 4; ++r) {
        int rl = rt * 16 + kg * 4 + r;
        float am = __uint_as_float(rmaxu[rl]);
        float inv = am > 0.f ? 127.f / am : 0.f;
        int grow = row0 + rl;
        if (grow < N) {
#pragma unroll
            for (int c = 0; c < 4; ++c)
                Y[(size_t)grow * 128 + (ctb + c) * 16 + m] =
                    (signed char)__float2int_rn(acc[c][r] * inv);
            if (ctb == 0 && m == 0) sc[grow] = am * (1.f / 127.f);
        }
    }
}

// C[64x40] = sa16 @ Wt2^T -> bf16 Y3 (unchanged precision)
static __device__ __forceinline__ void gemm40_mfma512(
    const unsigned short* sa16, const unsigned short* __restrict__ Wt2,
    unsigned short* __restrict__ Y3, int row0, int t, int N) {
    int l = t & 63, w = t >> 6;
    int rt = w & 3;
    int nct = (w < 4) ? 2 : 1;
    int ct0 = (w < 4) ? 0 : 2;
    int m = l & 15, kg = l >> 4;
    int row = rt * 16 + m;
    int rsw = row & 15;
    f32x4 acc[2] = {{0.f, 0.f, 0.f, 0.f}, {0.f, 0.f, 0.f, 0.f}};
#pragma unroll
    for (int ks = 0; ks < 4; ++ks) {
        bf16x8 a = *(const bf16x8*)&sa16[(size_t)row * 128 + (((ks * 4 + kg) ^ rsw) * 8)];
        int kk = ks * 32 + kg * 8;
        for (int c = 0; c < nct; ++c) {
            int n = (ct0 + c) * 16 + m;
            bf16x8 b = *(const bf16x8*)&Wt2[(size_t)n * 128 + kk];
            acc[c] = __builtin_amdgcn_mfma_f32_16x16x32_bf16(a, b, acc[c], 0, 0, 0);
        }
    }
    for (int c = 0; c < nct; ++c) {
        int col = (ct0 + c) * 16 + m;
        if (col >= 40) continue;
#pragma unroll
        for (int r = 0; r < 4; ++r) {
            int grow = row0 + rt * 16 + kg * 4 + r;
            if (grow < N) Y3[(size_t)grow * 40 + col] = f2bf(acc[c][r]);
        }
    }
}

// -------------------- int8 gather phase -> bf16 swizzled LDS (512 thr) ----
// 16 lanes per row (uint2 = 8B = 8 int8/lane), 4 rows per wave, 4-wide unroll.
template <int MODE>
static __device__ __forceinline__ void gather_phase_i8(
    const signed char* __restrict__ Ysrc, const float* __restrict__ scs,
    unsigned short* sa16,
    const int* __restrict__ csr, const int* __restrict__ indeg,
    const int* __restrict__ outdeg, int row0, int t, int N) {
    int w = t >> 6;             // wave 0..7
    int l = t & 63;
    int q = l >> 4;             // quarter 0..3 (one row each)
    int lq = l & 15;            // lane within quarter
    int qb = q * 16;            // quarter's base lane in wave

#pragma unroll
    for (int i = 0; i < 2; ++i) {
        int r = i * 32 + w * 4 + q;   // 0..63
        int node = row0 + r;
        bool valid = node < N;
        int d = 0;
        if (valid) d = indeg[node];
        int dc = d > MAXDEG ? MAXDEG : d;

        int idx0 = 0, idx1 = 0, idx2 = 0, idx3 = 0;
        if (valid) {
            const int* cp = csr + (size_t)node * MAXDEG;
            idx0 = cp[lq];
            if (dc > 16) idx1 = cp[16 + lq];
            if (dc > 32) idx2 = cp[32 + lq];
            if (dc > 48) idx3 = cp[48 + lq];
        }

        float a[8];
#pragma unroll
        for (int x = 0; x < 8; ++x) a[x] = 0.f;

#pragma unroll
        for (int c = 0; c < 4; ++c) {
            int ebase = c * 16;
            if (ebase >= dc) break;
            int v = (c == 0) ? idx0 : (c == 1) ? idx1 : (c == 2) ? idx2 : idx3;
            int lim = dc - ebase;
            if (lim > 16) lim = 16;
            int e = 0;
            for (; e + 4 <= lim; e += 4) {
                int s0 = __shfl(v, qb + e);
                int s1 = __shfl(v, qb + e + 1);
                int s2 = __shfl(v, qb + e + 2);
                int s3 = __shfl(v, qb + e + 3);
                uint2 u0 = *(const uint2*)&Ysrc[(size_t)s0 * 128 + lq * 8];
                uint2 u1 = *(const uint2*)&Ysrc[(size_t)s1 * 128 + lq * 8];
                uint2 u2 = *(const uint2*)&Ysrc[(size_t)s2 * 128 + lq * 8];
                uint2 u3 = *(const uint2*)&Ysrc[(size_t)s3 * 128 + lq * 8];
                float f0 = scs[s0], f1 = scs[s1], f2 = scs[s2], f3 = scs[s3];
                acci8(a, u0, f0); acci8(a, u1, f1);
                acci8(a, u2, f2); acci8(a, u3, f3);
            }
            for (; e < lim; ++e) {
                int s0 = __shfl(v, qb + e);
                uint2 u0 = *(const uint2*)&Ysrc[(size_t)s0 * 128 + lq * 8];
                acci8(a, u0, scs[s0]);
            }
        }

        if (valid) {
            int od = outdeg[node];
            float ln = rsqrtf((float)(od > 1 ? od : 1));
            if (MODE == 0) {
#pragma unroll
                for (int x = 0; x < 8; ++x) a[x] = fmaxf(a[x], 0.f) * ln;
            } else {
                float rn = rsqrtf((float)(d > 1 ? d : 1));
#pragma unroll
                for (int x = 0; x < 8; ++x) a[x] = fmaxf(a[x] * rn, 0.f) * ln;
            }
        }
        uint4 uo;
        uo.x = (unsigned)f2bf(a[0]) | ((unsigned)f2bf(a[1]) << 16);
        uo.y = (unsigned)f2bf(a[2]) | ((unsigned)f2bf(a[3]) << 16);
        uo.z = (unsigned)f2bf(a[4]) | ((unsigned)f2bf(a[5]) << 16);
        uo.w = (unsigned)f2bf(a[6]) | ((unsigned)f2bf(a[7]) << 16);
        int chunk = lq ^ (r & 15);
        *(uint4*)&sa16[(size_t)r * 128 + chunk * 8] = uo;
    }
}

// ==================== K1: edge bucketing || GEMM1 (MFMA, int8 out) ========
static __global__ __launch_bounds__(256) void bucket_gemm1_kernel(
    const float* __restrict__ A, const unsigned short* __restrict__ W1t,
    signed char* __restrict__ Y, float* __restrict__ s1,
    const int* __restrict__ src, const int* __restrict__ dst,
    int* __restrict__ cntD, int* __restrict__ cntS,
    unsigned int* __restrict__ bktD, unsigned char* __restrict__ bktS,
    int N, int E, int nb, int gG, int gB) {
    __shared__ unsigned short sa16[64 * 128];  // 16 KB; bucket role aliases
    int bid = blockIdx.x;
    int t = threadIdx.x;

    int nI = 5 * gB;
    int role, idx;
    if (bid < nI) {
        if (bid % 5 == 0) { role = 1; idx = bid / 5; }
        else { role = 0; idx = bid - bid / 5 - 1; }
    } else { role = 0; idx = bid - gB; }
    if (role == 1 && idx >= gB) return;
    if (role == 0 && idx >= gG) return;

    if (role == 1) {
        int* sh = (int*)sa16;    // 12 KB of the 16 KB
        int* hD = sh;
        int* hS = sh + 512;
        int* bD = sh + 1024;
        int* bS = sh + 1536;
        int* cD = sh + 2048;
        int* cS = sh + 2560;
        for (int i = t; i < 512; i += 256) {
            hD[i] = 0; hS[i] = 0; cD[i] = 0; cS[i] = 0;
        }
        __syncthreads();

        int base = idx * EPB + t * 16;
        int s_r[16], d_r[16];
        int nv = 0;
        if (base + 16 <= E) {
            nv = 16;
#pragma unroll
            for (int k = 0; k < 4; ++k) {
                int4 sv = *(const int4*)&src[base + k * 4];
                int4 dv = *(const int4*)&dst[base + k * 4];
                s_r[k * 4 + 0] = sv.x; s_r[k * 4 + 1] = sv.y;
                s_r[k * 4 + 2] = sv.z; s_r[k * 4 + 3] = sv.w;
                d_r[k * 4 + 0] = dv.x; d_r[k * 4 + 1] = dv.y;
                d_r[k * 4 + 2] = dv.z; d_r[k * 4 + 3] = dv.w;
            }
        } else {
            nv = E - base; if (nv < 0) nv = 0; if (nv > 16) nv = 16;
#pragma unroll
            for (int k = 0; k < 16; ++k) {
                if (k < nv) { s_r[k] = src[base + k]; d_r[k] = dst[base + k]; }
                else { s_r[k] = 0; d_r[k] = 0; }
            }
        }

#pragma unroll
        for (int k = 0; k < 16; ++k) {
            if (k < nv) {
                atomicAdd(&hD[d_r[k] >> 8], 1);
                atomicAdd(&hS[s_r[k] >> 8], 1);
            }
        }
        __syncthreads();

        for (int b = t; b < nb; b += 256) {
            int h = hD[b];
            bD[b] = h ? atomicAdd(&cntD[b], h) : 0;
            int h2 = hS[b];
            bS[b] = h2 ? atomicAdd(&cntS[b], h2) : 0;
        }
        __syncthreads();

#pragma unroll
        for (int k = 0; k < 16; ++k) {
            if (k < nv) {
                int d = d_r[k], s = s_r[k];
                int bb = d >> 8;
                int p = atomicAdd(&cD[bb], 1) + bD[bb];
                if (p < BCAP)
                    bktD[(size_t)bb * BCAP + p] =
                        ((unsigned int)(d & 255) << 17) | (unsigned int)s;
                int sb = s >> 8;
                int p2 = atomicAdd(&cS[sb], 1) + bS[sb];
                if (p2 < BCAP)
                    bktS[(size_t)sb * BCAP + p2] = (unsigned char)(s & 255);
            }
        }
        return;
    }

    // ---- gemm1: stage fp32 features -> bf16 swizzled LDS ----
    int row0 = idx * 64;
#pragma unroll
    for (int i = 0; i < 4; ++i) {
        int ci = i * 256 + t;
        int r = ci >> 4;
        int ch = ci & 15;
        int grow = row0 + r;
        uint4 uo = make_uint4(0u, 0u, 0u, 0u);
        if (grow < N) {
            float4 v0 = ld_f4(&A[(size_t)grow * 128 + ch * 8]);
            float4 v1 = ld_f4(&A[(size_t)grow * 128 + ch * 8 + 4]);
            uo.x = (unsigned)f2bf(v0.x) | ((unsigned)f2bf(v0.y) << 16);
            uo.y = (unsigned)f2bf(v0.z) | ((unsigned)f2bf(v0.w) << 16);
            uo.z = (unsigned)f2bf(v1.x) | ((unsigned)f2bf(v1.y) << 16);
            uo.w = (unsigned)f2bf(v1.z) | ((unsigned)f2bf(v1.w) << 16);
        }
        int chunk = ch ^ (r & 15);
        *(uint4*)&sa16[(size_t)r * 128 + chunk * 8] = uo;
    }
    __syncthreads();
    gemm128_mfma256_q(sa16, W1t, Y, s1, row0, t, N);
}

// ==================== K1b: per-bucket CSR build ====================
static __global__ __launch_bounds__(256) void csr_build_kernel(
    const int* __restrict__ cntD, const int* __restrict__ cntS,
    const unsigned int* __restrict__ bktD, const unsigned char* __restrict__ bktS,
    int* __restrict__ csr, int* __restrict__ indeg, int* __restrict__ outdeg,
    int N, int nb) {
    __shared__ int cur[256];
    int bid = blockIdx.x;
    int t = threadIdx.x;
    cur[t] = 0;
    __syncthreads();

    if (bid < nb) {
        int b = bid;
        int cnt = cntD[b]; if (cnt > BCAP) cnt = BCAP;
        const unsigned int* bp = bktD + (size_t)b * BCAP;
        for (int i = t; i < cnt; i += 256) {
            unsigned int v = bp[i];
            int d8 = v >> 17;
            int s = (int)(v & 0x1FFFFu);
            int p = atomicAdd(&cur[d8], 1);
            if (p < MAXDEG) csr[((size_t)(b * 256 + d8)) * MAXDEG + p] = s;
        }
        __syncthreads();
        int node = b * 256 + t;
        if (node < N) indeg[node] = cur[t];
    } else {
        int b = bid - nb;
        int cnt = cntS[b]; if (cnt > BCAP) cnt = BCAP;
        const unsigned char* bp = bktS + (size_t)b * BCAP;
        for (int i = t; i < cnt; i += 256) atomicAdd(&cur[bp[i]], 1);
        __syncthreads();
        int node = b * 256 + t;
        if (node < N) outdeg[node] = cur[t];
    }
}

// ==================== K2: agg(Y1 int8)+relu+ln @ Wh (MFMA, int8 out) ======
static __global__ __launch_bounds__(512) void agg_gemm2_kernel(
    const signed char* __restrict__ Y1, const float* __restrict__ s1,
    const unsigned short* __restrict__ WhT,
    signed char* __restrict__ Y2, float* __restrict__ s2,
    const int* __restrict__ csr, const int* __restrict__ indeg,
    const int* __restrict__ outdeg, int N) {
    __shared__ unsigned short sa16[64 * 128];  // 16 KB
    __shared__ unsigned rmaxu[64];
    int t = threadIdx.x;
    if (t < 64) rmaxu[t] = 0u;
    int row0 = blockIdx.x * 64;
    gather_phase_i8<0>(Y1, s1, sa16, csr, indeg, outdeg, row0, t, N);
    __syncthreads();
    gemm128_mfma512_q(sa16, WhT, Y2, s2, rmaxu, row0, t, N);
}

// ==================== K3: agg(Y2 int8)*rn,relu,*ln @ W2 (MFMA) ============
static __global__ __launch_bounds__(512) void agg_gemm3_kernel(
    const signed char* __restrict__ Y2, const float* __restrict__ s2,
    const unsigned short* __restrict__ Wt2,
    unsigned short* __restrict__ Y3,
    const int* __restrict__ csr, const int* __restrict__ indeg,
    const int* __restrict__ outdeg, int N) {
    __shared__ unsigned short sa16[64 * 128];  // 16 KB
    int t = threadIdx.x;
    int row0 = blockIdx.x * 64;
    gather_phase_i8<1>(Y2, s2, sa16, csr, indeg, outdeg, row0, t, N);
    __syncthreads();
    gemm40_mfma512(sa16, Wt2, Y3, row0, t, N);
}

// ========== K4: agg(Y3)*rn + b2 + log_softmax ==========
static __global__ __launch_bounds__(512) void agg40_lsm_kernel(
    const unsigned short* __restrict__ Y3, const float* __restrict__ b2,
    const int* __restrict__ csr, const int* __restrict__ indeg,
    float* __restrict__ out, int N) {
    int t = threadIdx.x;
    int node = blockIdx.x * 8 + (t >> 6);
    if (node >= N) return;
    int lane = t & 63;
    int grp = lane >> 4;
    int sub = lane & 15;
    int d = indeg[node];
    int dc = d > MAXDEG ? MAXDEG : d;

    float a0 = 0.f, a1 = 0.f, a2 = 0.f, a3 = 0.f;
    if (sub < 10) {
        const int* cp = csr + (size_t)node * MAXDEG;
        int e = grp;
        for (; e + 12 < dc; e += 16) {
            int s0 = cp[e];
            int s1 = cp[e + 4];
            int s2 = cp[e + 8];
            int s3 = cp[e + 12];
            ushort4 u0 = *(const ushort4*)&Y3[(size_t)s0 * 40 + sub * 4];
            ushort4 u1 = *(const ushort4*)&Y3[(size_t)s1 * 40 + sub * 4];
            ushort4 u2 = *(const ushort4*)&Y3[(size_t)s2 * 40 + sub * 4];
            ushort4 u3 = *(const ushort4*)&Y3[(size_t)s3 * 40 + sub * 4];
            a0 += bf2f(u0.x) + bf2f(u1.x) + bf2f(u2.x) + bf2f(u3.x);
            a1 += bf2f(u0.y) + bf2f(u1.y) + bf2f(u2.y) + bf2f(u3.y);
            a2 += bf2f(u0.z) + bf2f(u1.z) + bf2f(u2.z) + bf2f(u3.z);
            a3 += bf2f(u0.w) + bf2f(u1.w) + bf2f(u2.w) + bf2f(u3.w);
        }
        for (; e < dc; e += 4) {
            int s = cp[e];
            ushort4 u = *(const ushort4*)&Y3[(size_t)s * 40 + sub * 4];
            a0 += bf2f(u.x); a1 += bf2f(u.y); a2 += bf2f(u.z); a3 += bf2f(u.w);
        }
    }
    a0 += __shfl_xor(a0, 16); a0 += __shfl_xor(a0, 32);
    a1 += __shfl_xor(a1, 16); a1 += __shfl_xor(a1, 32);
    a2 += __shfl_xor(a2, 16); a2 += __shfl_xor(a2, 32);
    a3 += __shfl_xor(a3, 16); a3 += __shfl_xor(a3, 32);

    float rs = rsqrtf((float)(d > 1 ? d : 1));
    float x0 = 0.f, x1 = 0.f, x2 = 0.f, x3 = 0.f;
    float mx = -INFINITY;
    if (sub < 10) {
        float4 b = *(const float4*)&b2[sub * 4];
        x0 = a0 * rs + b.x;
        x1 = a1 * rs + b.y;
        x2 = a2 * rs + b.z;
        x3 = a3 * rs + b.w;
        mx = fmaxf(fmaxf(x0, x1), fmaxf(x2, x3));
    }
#pragma unroll
    for (int o = 1; o < 16; o <<= 1) mx = fmaxf(mx, __shfl_xor(mx, o));
    float ex = 0.f;
    if (sub < 10)
        ex = expf(x0 - mx) + expf(x1 - mx) + expf(x2 - mx) + expf(x3 - mx);
#pragma unroll
    for (int o = 1; o < 16; o <<= 1) ex += __shfl_xor(ex, o);
    float ls = logf(ex) + mx;
    if (sub < 10 && grp == 0)
        *(float4*)&out[(size_t)node * 40 + sub * 4] =
            make_float4(x0 - ls, x1 - ls, x2 - ls, x3 - ls);
}

// -------------------- launch --------------------

extern "C" void kernel_launch(void* const* d_in, const int* in_sizes, int n_in,
                              void* d_out, int out_size, void* d_ws, size_t ws_size,
                              hipStream_t stream) {
    const float* features = (const float*)d_in[0];
    const int* src = (const int*)d_in[1];
    const int* dst = (const int*)d_in[2];
    const float* W1 = (const float*)d_in[3];
    const float* Wh = (const float*)d_in[4];
    const float* W2 = (const float*)d_in[5];
    const float* b2 = (const float*)d_in[6];
    float* out = (float*)d_out;

    const int N = in_sizes[0] / 128;
    const int E = in_sizes[1];
    const int nb = (N + 255) / 256;

    char* p = (char*)d_ws;
    auto carve = [&](size_t bytes) {
        char* q = p;
        p += (bytes + 255) & ~(size_t)255;
        return q;
    };
    signed char* bufY1 = (signed char*)carve((size_t)N * 128);
    float* sc1 = (float*)carve((size_t)N * 4);
    signed char* bufY2 = (signed char*)carve((size_t)N * 128);
    float* sc2 = (float*)carve((size_t)N * 4);
    unsigned short* bufY3 = (unsigned short*)carve((size_t)N * 40 * 2);
    int* csr = (int*)carve((size_t)N * MAXDEG * 4);
    unsigned int* bktD = (unsigned int*)carve((size_t)nb * BCAP * 4);
    unsigned char* bktS = (unsigned char*)carve((size_t)nb * BCAP);
    int* cntD = (int*)carve((size_t)nb * 4);
    int* cntS = (int*)carve((size_t)nb * 4);
    int* indeg = (int*)carve((size_t)N * 4);
    int* outdeg = (int*)carve((size_t)N * 4);
    unsigned short* W1t = (unsigned short*)carve((size_t)128 * 128 * 2);
    unsigned short* WhT = (unsigned short*)carve((size_t)128 * 128 * 2);
    unsigned short* Wt2 = (unsigned short*)carve((size_t)48 * 128 * 2);
    (void)ws_size; (void)n_in; (void)out_size;

    hipMemsetAsync(cntD, 0, (size_t)nb * 4, stream);
    hipMemsetAsync(cntS, 0, (size_t)nb * 4, stream);

    int gG = (N + 63) / 64;
    int gB = (E + EPB - 1) / EPB;
    // K0: weight transposes (bf16)
    wtrans_kernel<<<3, 256, 0, stream>>>(W1, Wh, W2, W1t, WhT, Wt2);
    // K1: edge bucketing || gemm1 (MFMA, int8+scale out)
    bucket_gemm1_kernel<<<gG + gB, 256, 0, stream>>>(
        features, W1t, bufY1, sc1, src, dst, cntD, cntS, bktD, bktS,
        N, E, nb, gG, gB);
    // K1b: per-bucket CSR/indeg/outdeg
    csr_build_kernel<<<2 * nb, 256, 0, stream>>>(
        cntD, cntS, bktD, bktS, csr, indeg, outdeg, N, nb);
    // K2: Y2 = (relu(agg(Y1)) * ln) @ Wh   (int8 gather, MFMA, int8 out)
    agg_gemm2_kernel<<<gG, 512, 0, stream>>>(bufY1, sc1, WhT, bufY2, sc2,
                                             csr, indeg, outdeg, N);
    // K3: Y3 = (relu(agg(Y2) * rn) * ln) @ W2  (int8 gather, MFMA)
    agg_gemm3_kernel<<<gG, 512, 0, stream>>>(bufY2, sc2, Wt2, bufY3,
                                             csr, indeg, outdeg, N);
    // K4: out = log_softmax(agg(Y3) * rn + b2)
    agg40_lsm_kernel<<<(N + 7) / 8, 512, 0, stream>>>(bufY3, b2, csr, indeg, out, N);
}